// Round 4
// baseline (378.698 us; speedup 1.0000x reference)
//
#include <hip/hip_runtime.h>
#include <stdint.h>
#include <math.h>

#define HW_ 16384   // H*W = 128*128
#define C_  256
#define NT  8       // tiles per block (each tile = 64 positions)

typedef short bf16x8 __attribute__((ext_vector_type(8)));
typedef float f32x4  __attribute__((ext_vector_type(4)));
typedef unsigned int u32;

__device__ __forceinline__ unsigned short f2bf(float f) {
  union { float f; unsigned u; } v; v.f = f;
  unsigned u = v.u;
  u += 0x7fffu + ((u >> 16) & 1u);   // RNE
  return (unsigned short)(u >> 16);
}

// -------- kernel 0: prep (W -> bf16 in MFMA-fragment order, BN consts) ------
// Wp layout: idx = ks*8192 + kg*2048 + mf*128 + r*8 + e  (shorts)
__global__ __launch_bounds__(256) void k0_prep(
    const float* __restrict__ w_fe, const float* __restrict__ gamma,
    const float* __restrict__ beta, const float* __restrict__ mean,
    const float* __restrict__ var, unsigned short* __restrict__ Wp,
    float* __restrict__ scale, float* __restrict__ shift)
{
  int i = blockIdx.x * 256 + threadIdx.x;
  if (i < 131072) {
    int e  = i & 7;
    int r  = (i >> 3) & 15;
    int mf = (i >> 7) & 15;
    int kg = (i >> 11) & 3;
    int ks = i >> 13;
    int row = mf * 16 + r;              // output channel
    int k   = ks * 32 + kg * 8 + e;     // input channel (0..511)
    Wp[i] = f2bf(w_fe[row * 512 + k]);
  }
  if (i < 256) {
    float sc = gamma[i] * rsqrtf(var[i] + 1e-5f);
    scale[i] = sc;
    shift[i] = beta[i] - mean[i] * sc;
  }
}

// ------- kernel 1: persistent-W bf16 MFMA GEMM + BN + ReLU + pool -------
// 1024 thr = 16 waves; wave w = m-frag w (channels w*16..+16). A-frags in
// registers for the whole kernel. X tile [512 k x 64 pos] bf16 k-major in
// LDS, XOR-swizzled, double-buffered. One barrier per tile. Grid: 256.
__global__ __launch_bounds__(1024) void k1_gemm_pool(
    const float* __restrict__ x1, const float* __restrict__ x2,
    const unsigned short* __restrict__ Wp,
    const float* __restrict__ scale, const float* __restrict__ shift,
    float* __restrict__ pool_part)
{
  __shared__ unsigned short Bl[2][32768];   // 2 x 64KB, [pos][k] bf16 swizzled

  const int tid  = threadIdx.x;
  const int wave = tid >> 6;        // = mf
  const int lane = tid & 63;
  const int r15  = lane & 15;
  const int kg   = lane >> 4;
  const int blk  = blockIdx.x;
  const int b    = blk >> 5;                 // batch
  const int tile0 = (blk & 31) * NT;

  const float* xb1 = x1 + (size_t)b * C_ * HW_;
  const float* xb2 = x2 + (size_t)b * C_ * HW_;

  // ---- A-frags once for this wave (64 VGPRs) ----
  bf16x8 Af[16];
#pragma unroll
  for (int ks = 0; ks < 16; ++ks)
    Af[ks] = *(const bf16x8*)(Wp + ks * 8192 + kg * 2048 + wave * 128 + r15 * 8);

  const int chbase = wave * 16 + kg * 4;
  const float4 sc4 = *(const float4*)&scale[chbase];
  const float4 sh4 = *(const float4*)&shift[chbase];

  float pool0 = 0.f, pool1 = 0.f, pool2 = 0.f, pool3 = 0.f;

  // staging decomposition: thread -> (v,u); per quad q: w2 = q*16 + wave
  const int v = tid & 7;
  const int u = (tid >> 3) & 7;

  // frag-read lane constants
  const int rb_lane = r15 * 1024 + kg * 16;
  const int swz     = (r15 & 7) << 4;

  float2 ga[4], gb[4];

// H: 0 => k 0..255 (x1), 1 => k 256..511 (x2). P0: tile base position.
#define ISSUE_HALF(H, P0)                                                     \
  {                                                                           \
    _Pragma("unroll")                                                         \
    for (int q = 0; q < 4; ++q) {                                             \
      int w2 = q * 16 + wave;                                                 \
      int kp = (w2 & 15) * 8 + v;          /* 0..127 local k-pair */          \
      int pp = (w2 >> 4) * 8 + u;          /* 0..31 pos-pair */               \
      const float* src = ((H) == 0 ? xb1 : xb2) + (size_t)(kp * 2) * HW_      \
                         + (P0) + pp * 2;                                     \
      ga[q] = *(const float2*)src;                                            \
      gb[q] = *(const float2*)(src + HW_);                                    \
    }                                                                         \
  }

#define WRITE_HALF(H, BUF)                                                    \
  {                                                                           \
    _Pragma("unroll")                                                         \
    for (int q = 0; q < 4; ++q) {                                             \
      int w2 = q * 16 + wave;                                                 \
      int kp = (w2 & 15) * 8 + v;                                             \
      int pp = (w2 >> 4) * 8 + u;                                             \
      int pa = pp * 2, pb = pp * 2 + 1;                                       \
      int kb = (H) * 512 + kp * 4;         /* byte offset within row */       \
      u32 w0 = (u32)f2bf(ga[q].x) | ((u32)f2bf(gb[q].x) << 16);               \
      u32 w1 = (u32)f2bf(ga[q].y) | ((u32)f2bf(gb[q].y) << 16);               \
      *(u32*)((char*)(BUF) + ((pa * 1024 + kb) ^ ((pa & 7) << 4))) = w0;      \
      *(u32*)((char*)(BUF) + ((pb * 1024 + kb) ^ ((pb & 7) << 4))) = w1;      \
    }                                                                         \
  }

#define COMPUTE_HALF(H, BUF)                                                  \
  {                                                                           \
    _Pragma("unroll")                                                         \
    for (int ks8 = 0; ks8 < 8; ++ks8) {                                       \
      const int ks = (H) * 8 + ks8;                                           \
      _Pragma("unroll")                                                       \
      for (int nf = 0; nf < 4; ++nf) {                                        \
        int byte = rb_lane + nf * 16384 + ks * 64;                            \
        bf16x8 bfr = *(const bf16x8*)((const char*)(BUF) + (byte ^ swz));     \
        acc[nf] = __builtin_amdgcn_mfma_f32_16x16x32_bf16(Af[ks], bfr,        \
                                                          acc[nf], 0, 0, 0); \
      }                                                                       \
    }                                                                         \
  }

  // ---- prologue: stage tile0 into buf 0 ----
  {
    const int p0 = tile0 * 64;
    ISSUE_HALF(0, p0) WRITE_HALF(0, Bl[0])
    ISSUE_HALF(1, p0) WRITE_HALF(1, Bl[0])
  }
  __syncthreads();

  int cur = 0;
  for (int tt = 0; tt < NT; ++tt) {
    f32x4 acc[4];
#pragma unroll
    for (int nf = 0; nf < 4; ++nf) acc[nf] = (f32x4){0.f, 0.f, 0.f, 0.f};

    const int p0n = (tile0 + tt + 1) * 64;
    const bool more = (tt + 1 < NT);

    if (more) ISSUE_HALF(0, p0n)
    COMPUTE_HALF(0, Bl[cur])
    if (more) { WRITE_HALF(0, Bl[cur ^ 1]) ISSUE_HALF(1, p0n) }
    COMPUTE_HALF(1, Bl[cur])
    if (more) WRITE_HALF(1, Bl[cur ^ 1])

    // pool accumulate: BN + ReLU, sum over this tile's columns held in acc
#pragma unroll
    for (int nf = 0; nf < 4; ++nf) {
      pool0 += fmaxf(acc[nf][0] * sc4.x + sh4.x, 0.f);
      pool1 += fmaxf(acc[nf][1] * sc4.y + sh4.y, 0.f);
      pool2 += fmaxf(acc[nf][2] * sc4.z + sh4.z, 0.f);
      pool3 += fmaxf(acc[nf][3] * sc4.w + sh4.w, 0.f);
    }
    __syncthreads();
    cur ^= 1;
  }

  // reduce over the 16 columns (r15 lanes) of each wave group
#pragma unroll
  for (int m = 1; m < 16; m <<= 1) {
    pool0 += __shfl_xor(pool0, m);
    pool1 += __shfl_xor(pool1, m);
    pool2 += __shfl_xor(pool2, m);
    pool3 += __shfl_xor(pool3, m);
  }
  if (r15 == 0) {
    float* dst = pool_part + (size_t)blk * 256 + chbase;
    dst[0] = pool0; dst[1] = pool1; dst[2] = pool2; dst[3] = pool3;
  }
}

// -------- kernel 2: tiny MLPs -> per-(b,c) 3x3 kernels + attn coefs --------
__global__ __launch_bounds__(256) void k2_small(
    const float* __restrict__ pool_part,
    const float* __restrict__ w_cg1, const float* __restrict__ w_cg2,
    const float* __restrict__ w_ag1, const float* __restrict__ w_ag2,
    float* __restrict__ cw, float* __restrict__ coef)
{
  __shared__ float pl[256];
  __shared__ float hl[64];
  __shared__ float al[64];
  const int b = blockIdx.x, t = threadIdx.x;
  float s = 0.f;
  const float* base = pool_part + (size_t)b * 32 * 256 + t;
  for (int blk = 0; blk < 32; ++blk) s += base[blk * 256];   // fixed order
  pl[t] = s * (1.0f / 16384.0f);
  __syncthreads();
  if (t < 64) {
    float h = 0.f, a = 0.f;
    for (int i = 0; i < 256; ++i) {
      float p = pl[i];
      h += p * w_cg1[t * 256 + i];
      a += p * w_ag1[t * 256 + i];
    }
    hl[t] = fmaxf(h, 0.f);
    al[t] = fmaxf(a, 0.f);
  }
  __syncthreads();
#pragma unroll
  for (int e = 0; e < 9; ++e) {
    int o = e * 256 + t;                 // o in [0,2304) = c*9 + tap
    float acc = 0.f;
    for (int j = 0; j < 64; ++j) acc += hl[j] * w_cg2[o * 64 + j];
    cw[b * 2304 + o] = acc;
  }
  if (t < 2) {
    float acc = 0.f;
    for (int j = 0; j < 64; ++j) acc += al[j] * w_ag2[t * 64 + j];
    coef[b * 2 + t] = 0.25f / (1.0f + expf(-acc));   // 0.25 = LAMBDA_S*LAMBDA_C
  }
}

// -------- kernel 3: depthwise 3x3 (same kernel on x1 & x2) + combine --------
__global__ __launch_bounds__(256) void k3_dynconv(
    const float* __restrict__ x1, const float* __restrict__ x2,
    const float* __restrict__ cw, const float* __restrict__ coef,
    float* __restrict__ out)
{
  __shared__ float t1[34 * 128];
  __shared__ float t2[34 * 128];
  const int tid   = threadIdx.x;
  const int blk   = blockIdx.x;
  const int strip = blk & 3;
  const int c     = (blk >> 2) & 255;
  const int b     = blk >> 10;
  const int h0    = strip * 32;

  const size_t plane = ((size_t)b * C_ + c) * HW_;
  const float* p1 = x1 + plane;
  const float* p2 = x2 + plane;

  float tp[9];
#pragma unroll
  for (int e = 0; e < 9; ++e) tp[e] = cw[(b * C_ + c) * 9 + e];
  const float c1 = coef[b * 2 + 0];
  const float c2 = coef[b * 2 + 1];

  for (int f = tid; f < 1088; f += 256) {
    int row = f >> 5;
    int c4  = (f & 31) << 2;
    int gh  = h0 - 1 + row;
    float4 v1 = make_float4(0.f, 0.f, 0.f, 0.f), v2 = v1;
    if (gh >= 0 && gh < 128) {
      v1 = *(const float4*)&p1[gh * 128 + c4];
      v2 = *(const float4*)&p2[gh * 128 + c4];
    }
    *(float4*)&t1[row * 128 + c4] = v1;
    *(float4*)&t2[row * 128 + c4] = v2;
  }
  __syncthreads();

  for (int i = 0; i < 16; ++i) {
    int q   = tid + i * 256;
    int r   = q >> 7;
    int col = q & 127;
    int lr  = r + 1;
    const bool lok = col > 0, rok = col < 127;
    float d1 = 0.f, d2 = 0.f;
#pragma unroll
    for (int dy = 0; dy < 3; ++dy) {
      const float* row1 = &t1[(lr - 1 + dy) * 128];
      const float* row2 = &t2[(lr - 1 + dy) * 128];
      float a1v = lok ? row1[col - 1] : 0.f;
      float b1v = row1[col];
      float e1v = rok ? row1[col + 1] : 0.f;
      float a2v = lok ? row2[col - 1] : 0.f;
      float b2v = row2[col];
      float e2v = rok ? row2[col + 1] : 0.f;
      d1 += a1v * tp[dy * 3 + 0] + b1v * tp[dy * 3 + 1] + e1v * tp[dy * 3 + 2];
      d2 += a2v * tp[dy * 3 + 0] + b2v * tp[dy * 3 + 1] + e2v * tp[dy * 3 + 2];
    }
    float v1 = t1[lr * 128 + col];
    float v2 = t2[lr * 128 + col];
    out[plane + (size_t)(h0 + r) * 128 + col] = 0.5f * (v1 + v2) + c1 * d1 + c2 * d2;
  }
}

extern "C" void kernel_launch(void* const* d_in, const int* in_sizes, int n_in,
                              void* d_out, int out_size, void* d_ws, size_t ws_size,
                              hipStream_t stream) {
  const float* x1    = (const float*)d_in[0];
  const float* x2    = (const float*)d_in[1];
  const float* w_fe  = (const float*)d_in[2];
  const float* gamma = (const float*)d_in[3];
  const float* beta  = (const float*)d_in[4];
  const float* mean  = (const float*)d_in[5];
  const float* var   = (const float*)d_in[6];
  const float* w_cg1 = (const float*)d_in[7];
  const float* w_cg2 = (const float*)d_in[8];
  const float* w_ag1 = (const float*)d_in[9];
  const float* w_ag2 = (const float*)d_in[10];
  float* out = (float*)d_out;

  // workspace layout (~600 KB; harness gave >= 2.4 MB previously)
  char* ws = (char*)d_ws;
  unsigned short* Wp = (unsigned short*)(ws);              // [0, 262144)
  float* scale     = (float*)(ws + 262144);                // 1 KB
  float* shift     = (float*)(ws + 263168);                // 1 KB
  float* pool_part = (float*)(ws + 264192);                // 256*256*4 = 256 KB
  float* cw        = (float*)(ws + 526336);                // 73728 B
  float* coef      = (float*)(ws + 600064);                // 64 B

  k0_prep<<<512, 256, 0, stream>>>(w_fe, gamma, beta, mean, var, Wp, scale, shift);
  k1_gemm_pool<<<256, 1024, 0, stream>>>(x1, x2, Wp, scale, shift, pool_part);
  k2_small<<<8, 256, 0, stream>>>(pool_part, w_cg1, w_cg2, w_ag1, w_ag2, cw, coef);
  k3_dynconv<<<8192, 256, 0, stream>>>(x1, x2, cw, coef, out);
}

// Round 5
// 202.984 us; speedup vs baseline: 1.8657x; 1.8657x over previous
//
#include <hip/hip_runtime.h>
#include <stdint.h>
#include <math.h>

#define HW_ 16384   // H*W = 128*128
#define C_  256
#define NT  8       // tiles per block (each tile = 64 positions)
#define ROWB 1040   // LDS bytes per position-row: 1024 data + 16 pad

typedef short bf16x8 __attribute__((ext_vector_type(8)));
typedef float f32x4  __attribute__((ext_vector_type(4)));
typedef unsigned int u32;

__device__ __forceinline__ unsigned short f2bf(float f) {
  union { float f; unsigned u; } v; v.f = f;
  unsigned u = v.u;
  u += 0x7fffu + ((u >> 16) & 1u);   // RNE
  return (unsigned short)(u >> 16);
}

// -------- kernel 0: prep (W -> bf16 in MFMA-fragment order, BN consts) ------
// Wp layout: idx = ks*8192 + kg*2048 + mf*128 + r*8 + e  (shorts)
__global__ __launch_bounds__(256) void k0_prep(
    const float* __restrict__ w_fe, const float* __restrict__ gamma,
    const float* __restrict__ beta, const float* __restrict__ mean,
    const float* __restrict__ var, unsigned short* __restrict__ Wp,
    float* __restrict__ scale, float* __restrict__ shift)
{
  int i = blockIdx.x * 256 + threadIdx.x;
  if (i < 131072) {
    int e  = i & 7;
    int r  = (i >> 3) & 15;
    int mf = (i >> 7) & 15;
    int kg = (i >> 11) & 3;
    int ks = i >> 13;
    int row = mf * 16 + r;              // output channel
    int k   = ks * 32 + kg * 8 + e;     // input channel (0..511)
    Wp[i] = f2bf(w_fe[row * 512 + k]);
  }
  if (i < 256) {
    float sc = gamma[i] * rsqrtf(var[i] + 1e-5f);
    scale[i] = sc;
    shift[i] = beta[i] - mean[i] * sc;
  }
}

// ------- kernel 1: persistent-W bf16 MFMA GEMM + BN + ReLU + pool -------
// 1024 thr = 16 waves; wave w = m-frag w (channels w*16..+16). A-frags in
// registers for the whole kernel (launch_bounds(1024,4) -> 128 VGPR cap,
// 1 block/CU). X tile [64 pos][512 k] bf16 in LDS, +16B row pad
// (conflict-free b128 reads), double-buffered. One barrier per tile.
__global__ __launch_bounds__(1024, 4) void k1_gemm_pool(
    const float* __restrict__ x1, const float* __restrict__ x2,
    const unsigned short* __restrict__ Wp,
    const float* __restrict__ scale, const float* __restrict__ shift,
    float* __restrict__ pool_part)
{
  __shared__ __align__(16) char Bl[2][64 * ROWB];   // 2 x 66560 B

  const int tid  = threadIdx.x;
  const int wave = tid >> 6;        // = mf
  const int lane = tid & 63;
  const int r15  = lane & 15;
  const int kg   = lane >> 4;
  const int blk  = blockIdx.x;
  const int b    = blk >> 5;                 // batch
  const int tile0 = (blk & 31) * NT;

  const float* xb1 = x1 + (size_t)b * C_ * HW_;
  const float* xb2 = x2 + (size_t)b * C_ * HW_;

  // staging decomposition: v -> k-pair fine index, u -> pos-pair fine index
  const int v  = tid & 7;
  const int u2 = ((tid >> 3) & 7) * 2;
  const int kp = wave * 8 + v;        // k-pair 0..127 within a half
  const int kb = kp * 4;              // byte offset of (2kp) within row data

  const int kg16 = kg * 16;

  // ---- A-frags once for this wave (64 VGPRs) ----
  bf16x8 Af[16];
#pragma unroll
  for (int ks = 0; ks < 16; ++ks)
    Af[ks] = *(const bf16x8*)(Wp + ks * 8192 + kg * 2048 + wave * 128 + r15 * 8);

  const int chbase = wave * 16 + kg * 4;
  const float4 sc4 = *(const float4*)&scale[chbase];
  const float4 sh4 = *(const float4*)&shift[chbase];

  float pool0 = 0.f, pool1 = 0.f, pool2 = 0.f, pool3 = 0.f;

  float2 ga[2], gb[2];

// Load q-pair (Q0, Q0+1): 4 x float2, 8 full 64B segments per wave-instr.
#define ISSUE_P(H, P0, Q0)                                                    \
  {                                                                           \
    const float* xsrc = ((H) == 0 ? xb1 : xb2) + (size_t)(kp * 2) * HW_       \
                        + (P0) + (Q0) * 16 + u2;                              \
    ga[0] = *(const float2*)(xsrc);                                           \
    gb[0] = *(const float2*)(xsrc + HW_);                                     \
    ga[1] = *(const float2*)(xsrc + 16);                                      \
    gb[1] = *(const float2*)(xsrc + HW_ + 16);                                \
  }

// Pack (k,k+1) bf16 pairs, write 4 x b32 (2-way banked = free).
#define WRITE_P(H, BUF, Q0)                                                   \
  {                                                                           \
    char* wbase = (char*)(BUF) + kb + (H) * 512;                              \
    _Pragma("unroll")                                                         \
    for (int qi = 0; qi < 2; ++qi) {                                          \
      int pa = ((Q0) + qi) * 16 + u2;                                         \
      u32 w0 = (u32)f2bf(ga[qi].x) | ((u32)f2bf(gb[qi].x) << 16);             \
      u32 w1 = (u32)f2bf(ga[qi].y) | ((u32)f2bf(gb[qi].y) << 16);             \
      *(u32*)(wbase + pa * ROWB) = w0;                                        \
      *(u32*)(wbase + (pa + 1) * ROWB) = w1;                                  \
    }                                                                         \
  }

// 16 b128 reads + 16 MFMA (one quarter of a tile's K range).
#define COMPUTE_Q(H, BUF, KS0)                                                \
  {                                                                           \
    _Pragma("unroll")                                                         \
    for (int ks8 = (KS0); ks8 < (KS0) + 4; ++ks8) {                           \
      const int ks = (H) * 8 + ks8;                                           \
      const char* rbase = (const char*)(BUF) + ks * 64 + kg16 + r15 * ROWB;   \
      _Pragma("unroll")                                                       \
      for (int nf = 0; nf < 4; ++nf) {                                        \
        bf16x8 bfr = *(const bf16x8*)(rbase + nf * 16 * ROWB);                \
        acc[nf] = __builtin_amdgcn_mfma_f32_16x16x32_bf16(Af[ks], bfr,        \
                                                          acc[nf], 0, 0, 0); \
      }                                                                       \
    }                                                                         \
  }

  // ---- prologue: stage tile0 into buf 0 ----
  {
    const int p00 = tile0 * 64;
#pragma unroll
    for (int H = 0; H < 2; ++H) {
      ISSUE_P(H, p00, 0) WRITE_P(H, Bl[0], 0)
      ISSUE_P(H, p00, 2) WRITE_P(H, Bl[0], 2)
    }
  }
  __syncthreads();

  int cur = 0;
  for (int tt = 0; tt < NT; ++tt) {
    f32x4 acc[4];
#pragma unroll
    for (int nf = 0; nf < 4; ++nf) acc[nf] = (f32x4){0.f, 0.f, 0.f, 0.f};

    const int p0n = (tile0 + tt + 1) * 64;
    const bool more = (tt + 1 < NT);
    char* nxt = Bl[cur ^ 1];
    const char* cb = Bl[cur];

    if (more) ISSUE_P(0, p0n, 0)
    COMPUTE_Q(0, cb, 0)
    if (more) { WRITE_P(0, nxt, 0) ISSUE_P(0, p0n, 2) }
    COMPUTE_Q(0, cb, 4)
    if (more) { WRITE_P(0, nxt, 2) ISSUE_P(1, p0n, 0) }
    COMPUTE_Q(1, cb, 0)
    if (more) { WRITE_P(1, nxt, 0) ISSUE_P(1, p0n, 2) }
    COMPUTE_Q(1, cb, 4)
    if (more) WRITE_P(1, nxt, 2)

    // pool accumulate: BN + ReLU over this tile's 64 positions
#pragma unroll
    for (int nf = 0; nf < 4; ++nf) {
      pool0 += fmaxf(acc[nf][0] * sc4.x + sh4.x, 0.f);
      pool1 += fmaxf(acc[nf][1] * sc4.y + sh4.y, 0.f);
      pool2 += fmaxf(acc[nf][2] * sc4.z + sh4.z, 0.f);
      pool3 += fmaxf(acc[nf][3] * sc4.w + sh4.w, 0.f);
    }
    __syncthreads();
    cur ^= 1;
  }

  // reduce over the 16 positions (r15 lanes)
#pragma unroll
  for (int m = 1; m < 16; m <<= 1) {
    pool0 += __shfl_xor(pool0, m);
    pool1 += __shfl_xor(pool1, m);
    pool2 += __shfl_xor(pool2, m);
    pool3 += __shfl_xor(pool3, m);
  }
  if (r15 == 0) {
    float* dst = pool_part + (size_t)blk * 256 + chbase;
    dst[0] = pool0; dst[1] = pool1; dst[2] = pool2; dst[3] = pool3;
  }
}

// -------- kernel 2: tiny MLPs -> per-(b,c) 3x3 kernels + attn coefs --------
__global__ __launch_bounds__(256) void k2_small(
    const float* __restrict__ pool_part,
    const float* __restrict__ w_cg1, const float* __restrict__ w_cg2,
    const float* __restrict__ w_ag1, const float* __restrict__ w_ag2,
    float* __restrict__ cw, float* __restrict__ coef)
{
  __shared__ float pl[256];
  __shared__ float hl[64];
  __shared__ float al[64];
  const int b = blockIdx.x, t = threadIdx.x;
  float s = 0.f;
  const float* base = pool_part + (size_t)b * 32 * 256 + t;
  for (int blk = 0; blk < 32; ++blk) s += base[blk * 256];   // fixed order
  pl[t] = s * (1.0f / 16384.0f);
  __syncthreads();
  if (t < 64) {
    float h = 0.f, a = 0.f;
    for (int i = 0; i < 256; ++i) {
      float p = pl[i];
      h += p * w_cg1[t * 256 + i];
      a += p * w_ag1[t * 256 + i];
    }
    hl[t] = fmaxf(h, 0.f);
    al[t] = fmaxf(a, 0.f);
  }
  __syncthreads();
#pragma unroll
  for (int e = 0; e < 9; ++e) {
    int o = e * 256 + t;                 // o in [0,2304) = c*9 + tap
    float acc = 0.f;
    for (int j = 0; j < 64; ++j) acc += hl[j] * w_cg2[o * 64 + j];
    cw[b * 2304 + o] = acc;
  }
  if (t < 2) {
    float acc = 0.f;
    for (int j = 0; j < 64; ++j) acc += al[j] * w_ag2[t * 64 + j];
    coef[b * 2 + t] = 0.25f / (1.0f + expf(-acc));   // 0.25 = LAMBDA_S*LAMBDA_C
  }
}

// -------- kernel 3: depthwise 3x3 (same kernel on x1 & x2) + combine --------
__global__ __launch_bounds__(256) void k3_dynconv(
    const float* __restrict__ x1, const float* __restrict__ x2,
    const float* __restrict__ cw, const float* __restrict__ coef,
    float* __restrict__ out)
{
  __shared__ float t1[34 * 128];
  __shared__ float t2[34 * 128];
  const int tid   = threadIdx.x;
  const int blk   = blockIdx.x;
  const int strip = blk & 3;
  const int c     = (blk >> 2) & 255;
  const int b     = blk >> 10;
  const int h0    = strip * 32;

  const size_t plane = ((size_t)b * C_ + c) * HW_;
  const float* p1 = x1 + plane;
  const float* p2 = x2 + plane;

  float tp[9];
#pragma unroll
  for (int e = 0; e < 9; ++e) tp[e] = cw[(b * C_ + c) * 9 + e];
  const float c1 = coef[b * 2 + 0];
  const float c2 = coef[b * 2 + 1];

  for (int f = tid; f < 1088; f += 256) {
    int row = f >> 5;
    int c4  = (f & 31) << 2;
    int gh  = h0 - 1 + row;
    float4 v1 = make_float4(0.f, 0.f, 0.f, 0.f), v2 = v1;
    if (gh >= 0 && gh < 128) {
      v1 = *(const float4*)&p1[gh * 128 + c4];
      v2 = *(const float4*)&p2[gh * 128 + c4];
    }
    *(float4*)&t1[row * 128 + c4] = v1;
    *(float4*)&t2[row * 128 + c4] = v2;
  }
  __syncthreads();

  for (int i = 0; i < 16; ++i) {
    int q   = tid + i * 256;
    int r   = q >> 7;
    int col = q & 127;
    int lr  = r + 1;
    const bool lok = col > 0, rok = col < 127;
    float d1 = 0.f, d2 = 0.f;
#pragma unroll
    for (int dy = 0; dy < 3; ++dy) {
      const float* row1 = &t1[(lr - 1 + dy) * 128];
      const float* row2 = &t2[(lr - 1 + dy) * 128];
      float a1v = lok ? row1[col - 1] : 0.f;
      float b1v = row1[col];
      float e1v = rok ? row1[col + 1] : 0.f;
      float a2v = lok ? row2[col - 1] : 0.f;
      float b2v = row2[col];
      float e2v = rok ? row2[col + 1] : 0.f;
      d1 += a1v * tp[dy * 3 + 0] + b1v * tp[dy * 3 + 1] + e1v * tp[dy * 3 + 2];
      d2 += a2v * tp[dy * 3 + 0] + b2v * tp[dy * 3 + 1] + e2v * tp[dy * 3 + 2];
    }
    float v1 = t1[lr * 128 + col];
    float v2 = t2[lr * 128 + col];
    out[plane + (size_t)(h0 + r) * 128 + col] = 0.5f * (v1 + v2) + c1 * d1 + c2 * d2;
  }
}

extern "C" void kernel_launch(void* const* d_in, const int* in_sizes, int n_in,
                              void* d_out, int out_size, void* d_ws, size_t ws_size,
                              hipStream_t stream) {
  const float* x1    = (const float*)d_in[0];
  const float* x2    = (const float*)d_in[1];
  const float* w_fe  = (const float*)d_in[2];
  const float* gamma = (const float*)d_in[3];
  const float* beta  = (const float*)d_in[4];
  const float* mean  = (const float*)d_in[5];
  const float* var   = (const float*)d_in[6];
  const float* w_cg1 = (const float*)d_in[7];
  const float* w_cg2 = (const float*)d_in[8];
  const float* w_ag1 = (const float*)d_in[9];
  const float* w_ag2 = (const float*)d_in[10];
  float* out = (float*)d_out;

  // workspace layout (~600 KB)
  char* ws = (char*)d_ws;
  unsigned short* Wp = (unsigned short*)(ws);              // [0, 262144)
  float* scale     = (float*)(ws + 262144);                // 1 KB
  float* shift     = (float*)(ws + 263168);                // 1 KB
  float* pool_part = (float*)(ws + 264192);                // 256*256*4 = 256 KB
  float* cw        = (float*)(ws + 526336);                // 73728 B
  float* coef      = (float*)(ws + 600064);                // 64 B

  k0_prep<<<512, 256, 0, stream>>>(w_fe, gamma, beta, mean, var, Wp, scale, shift);
  k1_gemm_pool<<<256, 1024, 0, stream>>>(x1, x2, Wp, scale, shift, pool_part);
  k2_small<<<8, 256, 0, stream>>>(pool_part, w_cg1, w_cg2, w_ag1, w_ag2, cw, coef);
  k3_dynconv<<<8192, 256, 0, stream>>>(x1, x2, cw, coef, out);
}